// Round 7
// baseline (382.890 us; speedup 1.0000x reference)
//
#include <hip/hip_runtime.h>
#include <hip/hip_bf16.h>

#define NB 32
#define LV 1000
#define LQ 1200
#define VD 128
#define HID 512
#define NH 8
#define HD 64
#define LP 200    // len_pro = 0.2 * 1000
#define LQP 1216  // LQ padded to mult of 32
#define LPP 256   // LP padded
#define GM 4      // K-split slabs for pairM
#define GN 2      // K-split slabs for pairN

typedef __attribute__((ext_vector_type(8))) short s8v;   // 8 x bf16 (4 VGPR)
typedef __attribute__((ext_vector_type(4))) float f4v;   // 4 x f32 acc

union FragU { s8v v; unsigned short u[8]; };

__device__ __forceinline__ unsigned short f2bf(float f) {
    __hip_bfloat16 h = __float2bfloat16(f);
    return *reinterpret_cast<unsigned short*>(&h);
}

// ---------------------------------------------------------------------------
// K1: scores = max over 4 rows of att; stable top-200 via bitonic sort.
// ---------------------------------------------------------------------------
__global__ __launch_bounds__(1024) void topk_kernel(const float* __restrict__ att,
                                                    int* __restrict__ idx_ws,
                                                    float* __restrict__ out_idx) {
    __shared__ float s[1024];
    __shared__ int   si[1024];
    int b = blockIdx.x, tid = threadIdx.x;
    {
        float v = -INFINITY;
        if (tid < LV) {
            const float* p = att + (size_t)b * 4 * LV + tid;
            v = fmaxf(fmaxf(p[0], p[LV]), fmaxf(p[2 * LV], p[3 * LV]));
        }
        s[tid] = v; si[tid] = tid;
    }
    __syncthreads();
    for (int k = 2; k <= 1024; k <<= 1) {
        for (int j = k >> 1; j > 0; j >>= 1) {
            int i = tid, l = i ^ j;
            if (l > i) {
                float a = s[i], c = s[l];
                int ia = si[i], ic = si[l];
                bool aFirst = (a > c) || (a == c && ia < ic);
                bool desc = ((i & k) == 0);
                if (desc != aFirst) { s[i] = c; s[l] = a; si[i] = ic; si[l] = ia; }
            }
            __syncthreads();
        }
    }
    if (tid < LP) {
        int v = si[tid];
        idx_ws[b * LP + tid]  = v;
        out_idx[b * LP + tid] = (float)v;
    }
}

// ---------------------------------------------------------------------------
// K2: prep = pe_fill (blocks 0..599) + weight transpose (blocks 600..663)
// ---------------------------------------------------------------------------
__global__ __launch_bounds__(256) void prep_kernel(
    float* __restrict__ pe,
    const float* __restrict__ w0, const float* __restrict__ w1,
    const float* __restrict__ w2, const float* __restrict__ w3,
    unsigned short* __restrict__ t0, unsigned short* __restrict__ t1,
    unsigned short* __restrict__ t2, unsigned short* __restrict__ t3)
{
    __shared__ unsigned short Ts[64][72];
    int bx = blockIdx.x, tid = threadIdx.x;
    if (bx < 600) {
        int t = bx * 256 + tid;
        if (t < LQ * VD) {
            int r = t >> 7, c = t & 127;
            int i = c >> 1;
            float div = expf((float)(2 * i) * -0.07195578415606394f);
            float ang = (float)r * div;
            pe[t] = (c & 1) ? cosf(ang) : sinf(ang);
        }
        return;
    }
    int idx = bx - 600;          // 0..63
    int mat = idx >> 4, rem = idx & 15;
    int k0 = (rem & 1) * 64, n0 = (rem >> 1) * 64;
    const float* W; unsigned short* T;
    switch (mat) {
        case 0:  W = w0; T = t0; break;
        case 1:  W = w1; T = t1; break;
        case 2:  W = w2; T = t2; break;
        default: W = w3; T = t3; break;
    }
    #pragma unroll
    for (int e = 0; e < 2; ++e) {
        int flat = tid + e * 256;
        int kk = flat >> 3, n8 = (flat & 7) * 8;
        const float* p = W + (size_t)(k0 + kk) * HID + n0 + n8;
        float4 f0 = *(const float4*)p, f1 = *(const float4*)(p + 4);
        Ts[n8 + 0][kk] = f2bf(f0.x); Ts[n8 + 1][kk] = f2bf(f0.y);
        Ts[n8 + 2][kk] = f2bf(f0.z); Ts[n8 + 3][kk] = f2bf(f0.w);
        Ts[n8 + 4][kk] = f2bf(f1.x); Ts[n8 + 5][kk] = f2bf(f1.y);
        Ts[n8 + 6][kk] = f2bf(f1.z); Ts[n8 + 7][kk] = f2bf(f1.w);
    }
    __syncthreads();
    #pragma unroll
    for (int e = 0; e < 2; ++e) {
        int flat = tid + e * 256;
        int nn = flat >> 3, k8 = (flat & 7) * 8;
        uint4 pk;
        pk.x = (unsigned)Ts[nn][k8 + 0] | ((unsigned)Ts[nn][k8 + 1] << 16);
        pk.y = (unsigned)Ts[nn][k8 + 2] | ((unsigned)Ts[nn][k8 + 3] << 16);
        pk.z = (unsigned)Ts[nn][k8 + 4] | ((unsigned)Ts[nn][k8 + 5] << 16);
        pk.w = (unsigned)Ts[nn][k8 + 6] | ((unsigned)Ts[nn][k8 + 7] << 16);
        *(uint4*)&T[(size_t)(n0 + nn) * VD + k0 + k8] = pk;
    }
}

// ---------------------------------------------------------------------------
// K3: PEW[r][n] = pe[r] @ W + bias, in row-major (PW) and transposed (PWT)
// fp32 layouts. x<10 -> Wk variant (1216 rows), x>=10 -> Wq variant (256).
// Swapped MFMA so regs hold 4 consecutive n at fixed r.
// ---------------------------------------------------------------------------
__global__ __launch_bounds__(256) void pew_kernel(
    const float* __restrict__ pe,
    const unsigned short* __restrict__ Wkt, const unsigned short* __restrict__ Wqt,
    const float* __restrict__ bk, const float* __restrict__ bq,
    float* __restrict__ PEWk, float* __restrict__ PEWkT,
    float* __restrict__ PEWq, float* __restrict__ PEWqT)
{
    int x = blockIdx.x, yb = blockIdx.y;
    bool kMat = (x < 10);
    int rows = kMat ? LQ : LP;
    int Lpad = kMat ? LQP : LPP;
    const unsigned short* Wt = kMat ? Wkt : Wqt;
    const float* bias = kMat ? bk : bq;
    float* PW  = kMat ? PEWk : PEWq;
    float* PWT = kMat ? PEWkT : PEWqT;
    int xb = kMat ? x : x - 10;
    int lane = threadIdx.x & 63, w = threadIdx.x >> 6;
    int rbase = xb * 128 + (w >> 1) * 64;
    int nbase = yb * 128 + (w & 1) * 64;
    if (rbase >= Lpad) return;
    int lc = lane & 15, lg = lane >> 4;

    int prow[4];
    #pragma unroll
    for (int i = 0; i < 4; ++i) prow[i] = min(rbase + i * 16 + lc, rows - 1);

    f4v acc[4][4] = {};
    for (int kk = 0; kk < VD; kk += 32) {
        s8v af[4], bfr[4];
        #pragma unroll
        for (int i = 0; i < 4; ++i) {
            const float* pp = pe + (size_t)prow[i] * VD + kk + lg * 8;
            float4 f0 = *(const float4*)pp, f1 = *(const float4*)(pp + 4);
            FragU fu;
            fu.u[0]=f2bf(f0.x); fu.u[1]=f2bf(f0.y); fu.u[2]=f2bf(f0.z); fu.u[3]=f2bf(f0.w);
            fu.u[4]=f2bf(f1.x); fu.u[5]=f2bf(f1.y); fu.u[6]=f2bf(f1.z); fu.u[7]=f2bf(f1.w);
            af[i] = fu.v;
        }
        #pragma unroll
        for (int j = 0; j < 4; ++j)
            bfr[j] = *(const s8v*)&Wt[(size_t)(nbase + j * 16 + lc) * VD + kk + lg * 8];
        #pragma unroll
        for (int i = 0; i < 4; ++i)
            #pragma unroll
            for (int j = 0; j < 4; ++j)
                acc[i][j] = __builtin_amdgcn_mfma_f32_16x16x32_bf16(bfr[j], af[i], acc[i][j], 0, 0, 0);
    }
    #pragma unroll
    for (int i = 0; i < 4; ++i) {
        int r = rbase + i * 16 + lc;
        #pragma unroll
        for (int j = 0; j < 4; ++j) {
            int n0 = nbase + j * 16 + lg * 4;
            float4 b4 = *(const float4*)&bias[n0];
            float4 v = {acc[i][j][0] + b4.x, acc[i][j][1] + b4.y,
                        acc[i][j][2] + b4.z, acc[i][j][3] + b4.w};
            *(float4*)&PW[(size_t)r * HID + n0] = v;
            PWT[(size_t)(n0 + 0) * Lpad + r] = v.x;
            PWT[(size_t)(n0 + 1) * Lpad + r] = v.y;
            PWT[(size_t)(n0 + 2) * Lpad + r] = v.z;
            PWT[(size_t)(n0 + 3) * Lpad + r] = v.w;
        }
    }
}

// ---------------------------------------------------------------------------
// K4: all projections, one launch, no LDS. Per b: ids 0..95 = T-path
// (transposed out, unswapped MFMA), 96..143 = R-path (row-major, swapped).
// PE folded in via PEW epilogue adds (includes bias).
// ---------------------------------------------------------------------------
__global__ __launch_bounds__(256) void proj_kernel(
    const float* __restrict__ query, const float* __restrict__ key,
    const int* __restrict__ idxws,
    const unsigned short* __restrict__ Wqt, const unsigned short* __restrict__ Wkt,
    const unsigned short* __restrict__ Wv1t, const unsigned short* __restrict__ Wv2t,
    const float* __restrict__ bv1, const float* __restrict__ bv2,
    const float* __restrict__ PEWk, const float* __restrict__ PEWkT,
    const float* __restrict__ PEWq, const float* __restrict__ PEWqT,
    unsigned short* __restrict__ Qp, unsigned short* __restrict__ Kp,
    unsigned short* __restrict__ Qt, unsigned short* __restrict__ Kt,
    unsigned short* __restrict__ V1t, unsigned short* __restrict__ V2t)
{
    int id = blockIdx.x, b = blockIdx.z;
    bool Rp = (id >= 96);
    int p, xb;
    if (!Rp) {
        if (id < 40)      { p = 0; xb = id >> 2; }
        else if (id < 80) { p = 1; xb = (id - 40) >> 2; }
        else if (id < 88) { p = 2; xb = (id - 80) >> 2; }
        else              { p = 3; xb = (id - 88) >> 2; }
    } else {
        int t = id - 96;
        if (t < 40) { p = 0; xb = t >> 2; }
        else        { p = 2; xb = (t - 40) >> 2; }
    }
    int yb = id & 3;
    bool gath = (p >= 2);
    const float* src = gath ? query : key;
    int srcRows = gath ? LV : LQ;
    int rows = gath ? LP : LQ;
    int Lpad = gath ? LPP : LQP;
    const unsigned short* Wt = (p == 0) ? Wkt : (p == 1) ? Wv2t : (p == 2) ? Wqt : Wv1t;

    int lane = threadIdx.x & 63, w = threadIdx.x >> 6;
    int rbase = xb * 128 + (w >> 1) * 64;
    int nbase = yb * 128 + (w & 1) * 64;
    if (rbase >= Lpad) return;
    int lc = lane & 15, lg = lane >> 4;

    int srow[4];
    #pragma unroll
    for (int i = 0; i < 4; ++i) {
        int rc = min(rbase + i * 16 + lc, rows - 1);
        srow[i] = gath ? idxws[b * LP + rc] : rc;
    }

    if (!Rp) {
        unsigned short* dstT = (p == 0) ? Kt : (p == 1) ? V2t : (p == 2) ? Qt : V1t;
        const float* PWT  = (p == 0) ? PEWkT : (p == 2) ? PEWqT : nullptr;
        const float* bias = (p == 1) ? bv2 : bv1;
        bool usePE = (p == 0) || (p == 2);
        f4v acc[4][4] = {};
        for (int kk = 0; kk < VD; kk += 32) {
            s8v af[4], bfr[4];
            #pragma unroll
            for (int i = 0; i < 4; ++i) {
                const float* pp = src + ((size_t)b * srcRows + srow[i]) * VD + kk + lg * 8;
                float4 f0 = *(const float4*)pp, f1 = *(const float4*)(pp + 4);
                FragU fu;
                fu.u[0]=f2bf(f0.x); fu.u[1]=f2bf(f0.y); fu.u[2]=f2bf(f0.z); fu.u[3]=f2bf(f0.w);
                fu.u[4]=f2bf(f1.x); fu.u[5]=f2bf(f1.y); fu.u[6]=f2bf(f1.z); fu.u[7]=f2bf(f1.w);
                af[i] = fu.v;
            }
            #pragma unroll
            for (int j = 0; j < 4; ++j)
                bfr[j] = *(const s8v*)&Wt[(size_t)(nbase + j * 16 + lc) * VD + kk + lg * 8];
            #pragma unroll
            for (int i = 0; i < 4; ++i)
                #pragma unroll
                for (int j = 0; j < 4; ++j)
                    acc[i][j] = __builtin_amdgcn_mfma_f32_16x16x32_bf16(af[i], bfr[j], acc[i][j], 0, 0, 0);
        }
        float bbc[4];
        #pragma unroll
        for (int j = 0; j < 4; ++j) bbc[j] = usePE ? 0.f : bias[nbase + j * 16 + lc];
        #pragma unroll
        for (int i = 0; i < 4; ++i) {
            int rb = rbase + i * 16 + lg * 4;   // always <= Lpad-4
            #pragma unroll
            for (int j = 0; j < 4; ++j) {
                int n = nbase + j * 16 + lc;
                float a0, a1, a2, a3;
                if (usePE) {
                    float4 t4 = *(const float4*)&PWT[(size_t)n * Lpad + rb];
                    a0 = t4.x; a1 = t4.y; a2 = t4.z; a3 = t4.w;
                } else { a0 = a1 = a2 = a3 = bbc[j]; }
                unsigned short h0 = (rb + 0 < rows) ? f2bf(acc[i][j][0] + a0) : (unsigned short)0;
                unsigned short h1 = (rb + 1 < rows) ? f2bf(acc[i][j][1] + a1) : (unsigned short)0;
                unsigned short h2 = (rb + 2 < rows) ? f2bf(acc[i][j][2] + a2) : (unsigned short)0;
                unsigned short h3 = (rb + 3 < rows) ? f2bf(acc[i][j][3] + a3) : (unsigned short)0;
                uint2 pk;
                pk.x = (unsigned)h0 | ((unsigned)h1 << 16);
                pk.y = (unsigned)h2 | ((unsigned)h3 << 16);
                *(uint2*)&dstT[((size_t)b * HID + n) * Lpad + rb] = pk;
            }
        }
    } else {
        unsigned short* dst = (p == 0) ? Kp : Qp;
        const float* PW = (p == 0) ? PEWk : PEWq;
        f4v acc[4][4] = {};
        for (int kk = 0; kk < VD; kk += 32) {
            s8v af[4], bfr[4];
            #pragma unroll
            for (int i = 0; i < 4; ++i) {
                const float* pp = src + ((size_t)b * srcRows + srow[i]) * VD + kk + lg * 8;
                float4 f0 = *(const float4*)pp, f1 = *(const float4*)(pp + 4);
                FragU fu;
                fu.u[0]=f2bf(f0.x); fu.u[1]=f2bf(f0.y); fu.u[2]=f2bf(f0.z); fu.u[3]=f2bf(f0.w);
                fu.u[4]=f2bf(f1.x); fu.u[5]=f2bf(f1.y); fu.u[6]=f2bf(f1.z); fu.u[7]=f2bf(f1.w);
                af[i] = fu.v;
            }
            #pragma unroll
            for (int j = 0; j < 4; ++j)
                bfr[j] = *(const s8v*)&Wt[(size_t)(nbase + j * 16 + lc) * VD + kk + lg * 8];
            #pragma unroll
            for (int i = 0; i < 4; ++i)
                #pragma unroll
                for (int j = 0; j < 4; ++j)
                    acc[i][j] = __builtin_amdgcn_mfma_f32_16x16x32_bf16(bfr[j], af[i], acc[i][j], 0, 0, 0);
        }
        #pragma unroll
        for (int i = 0; i < 4; ++i) {
            int r = rbase + i * 16 + lc;
            if (r >= rows) continue;
            const float* pw = PW + (size_t)r * HID;
            unsigned short* dr = dst + ((size_t)b * rows + r) * HID;
            #pragma unroll
            for (int j = 0; j < 4; ++j) {
                int n0 = nbase + j * 16 + lg * 4;
                float4 a4 = *(const float4*)&pw[n0];
                uint2 pk;
                pk.x = (unsigned)f2bf(acc[i][j][0] + a4.x) |
                       ((unsigned)f2bf(acc[i][j][1] + a4.y) << 16);
                pk.y = (unsigned)f2bf(acc[i][j][2] + a4.z) |
                       ((unsigned)f2bf(acc[i][j][3] + a4.w) << 16);
                *(uint2*)&dr[n0] = pk;
            }
        }
    }
}

// ---------------------------------------------------------------------------
// K5: attn_avg[b,v,q] = (Qp[b,v,:].Kp[b,q,:]) / 64 — swapped MFMA so regs
// hold 4 consecutive q at fixed v: direct float4 stores, no LDS.
// ---------------------------------------------------------------------------
__global__ __launch_bounds__(256) void attnavg_kernel(
    const unsigned short* __restrict__ Qp, const unsigned short* __restrict__ Kp,
    float* __restrict__ outA)
{
    int b = blockIdx.z;
    int lane = threadIdx.x & 63, w = threadIdx.x >> 6;
    int vbase = blockIdx.y * 128 + (w >> 1) * 64;
    int qbase = blockIdx.x * 128 + (w & 1) * 64;
    if (qbase >= LQ || vbase >= LP) return;
    int lc = lane & 15, lg = lane >> 4;

    int qr[4], vr[4];
    #pragma unroll
    for (int i = 0; i < 4; ++i) qr[i] = min(qbase + i * 16 + lc, LQ - 1);
    #pragma unroll
    for (int j = 0; j < 4; ++j) vr[j] = min(vbase + j * 16 + lc, LP - 1);

    f4v acc[4][4] = {};   // acc[i=q-frag][j=v-frag]
    for (int kk = 0; kk < HID; kk += 32) {
        s8v af[4], bfr[4];
        #pragma unroll
        for (int i = 0; i < 4; ++i)
            af[i] = *(const s8v*)&Kp[((size_t)b * LQ + qr[i]) * HID + kk + lg * 8];
        #pragma unroll
        for (int j = 0; j < 4; ++j)
            bfr[j] = *(const s8v*)&Qp[((size_t)b * LP + vr[j]) * HID + kk + lg * 8];
        #pragma unroll
        for (int i = 0; i < 4; ++i)
            #pragma unroll
            for (int j = 0; j < 4; ++j)
                acc[i][j] = __builtin_amdgcn_mfma_f32_16x16x32_bf16(af[i], bfr[j], acc[i][j], 0, 0, 0);
    }
    const float sc = 1.0f / 64.0f;
    #pragma unroll
    for (int j = 0; j < 4; ++j) {
        int v = vbase + j * 16 + lc;
        if (v >= LP) continue;
        float* base = outA + ((size_t)b * LP + v) * LQ;
        #pragma unroll
        for (int i = 0; i < 4; ++i) {
            int q0 = qbase + i * 16 + lg * 4;
            if (q0 + 3 >= LQ) continue;
            float4 o = {acc[i][j][0] * sc, acc[i][j][1] * sc,
                        acc[i][j][2] * sc, acc[i][j][3] * sc};
            *(float4*)&base[q0] = o;
        }
    }
}

// ---------------------------------------------------------------------------
// K6: merged pair GEMMs: M = Kt~V2t (GM slabs), N = Qt~V1t (GN slabs).
// out[d][k] = sum_r A[r,d]*B[r,k]; swapped MFMA -> float4 stores.
// ---------------------------------------------------------------------------
__global__ __launch_bounds__(64) void pair_kernel(
    const unsigned short* __restrict__ Kt, const unsigned short* __restrict__ V2t,
    const unsigned short* __restrict__ Qt, const unsigned short* __restrict__ V1t,
    float* __restrict__ Mp, float* __restrict__ Np)
{
    int g = blockIdx.x;
    const unsigned short *At, *Bt; float* outP;
    int LPAD, NCH, G, slab;
    if (g < GM) { At = Kt; Bt = V2t; outP = Mp; LPAD = LQP; NCH = 38; G = GM; slab = g; }
    else        { At = Qt; Bt = V1t; outP = Np; LPAD = LPP; NCH = 8;  G = GN; slab = g - GM; }
    int bh = blockIdx.y, b = bh >> 3, h = bh & 7;
    int lane = threadIdx.x, lc = lane & 15, lg = lane >> 4;
    const unsigned short* Ah = At + ((size_t)b * HID + h * HD) * LPAD;
    const unsigned short* Bh = Bt + ((size_t)b * HID + h * HD) * LPAD;
    f4v acc[4][4] = {};
    for (int c = slab; c < NCH; c += G) {
        int r0 = c * 32 + lg * 8;
        s8v af[4], bfr[4];
        #pragma unroll
        for (int i = 0; i < 4; ++i)
            af[i] = *(const s8v*)&Ah[(size_t)(i * 16 + lc) * LPAD + r0];
        #pragma unroll
        for (int j = 0; j < 4; ++j)
            bfr[j] = *(const s8v*)&Bh[(size_t)(j * 16 + lc) * LPAD + r0];
        #pragma unroll
        for (int i = 0; i < 4; ++i)
            #pragma unroll
            for (int j = 0; j < 4; ++j)
                acc[i][j] = __builtin_amdgcn_mfma_f32_16x16x32_bf16(bfr[j], af[i], acc[i][j], 0, 0, 0);
    }
    float* op = outP + ((size_t)slab * 256 + bh) * 4096;
    #pragma unroll
    for (int i = 0; i < 4; ++i) {
        int d = i * 16 + lc;
        #pragma unroll
        for (int j = 0; j < 4; ++j) {
            int k0 = j * 16 + lg * 4;
            float4 o = {acc[i][j][0], acc[i][j][1], acc[i][j][2], acc[i][j][3]};
            *(float4*)&op[d * 64 + k0] = o;
        }
    }
}

// ---------------------------------------------------------------------------
// K7: x[b,h*64+k] = BN((1/8) sum_d (sum_g Mp)(sum_g Np))
// ---------------------------------------------------------------------------
__global__ __launch_bounds__(256) void xout_kernel(
    const float* __restrict__ Mp, const float* __restrict__ Np,
    const float* __restrict__ gamma, const float* __restrict__ beta,
    const float* __restrict__ mean, const float* __restrict__ var,
    float* __restrict__ outX)
{
    int bh = blockIdx.x, b = bh >> 3, h = bh & 7;
    int tid = threadIdx.x;
    int k = tid & 63, dg = tid >> 6;
    float s = 0.f;
    for (int d = dg * 16; d < dg * 16 + 16; ++d) {
        int o = d * 64 + k;
        float m = 0.f, n = 0.f;
        #pragma unroll
        for (int g = 0; g < GM; ++g) m += Mp[((size_t)g * 256 + bh) * 4096 + o];
        #pragma unroll
        for (int g = 0; g < GN; ++g) n += Np[((size_t)g * 256 + bh) * 4096 + o];
        s += m * n;
    }
    __shared__ float red[4][64];
    red[dg][k] = s;
    __syncthreads();
    if (tid < 64) {
        float x = (red[0][tid] + red[1][tid] + red[2][tid] + red[3][tid]) * 0.125f;
        int c = h * HD + tid;
        outX[(size_t)b * HID + c] =
            (x - mean[c]) * rsqrtf(var[c] + 1e-5f) * gamma[c] + beta[c];
    }
}

extern "C" void kernel_launch(void* const* d_in, const int* in_sizes, int n_in,
                              void* d_out, int out_size, void* d_ws, size_t ws_size,
                              hipStream_t stream) {
    const float* query = (const float*)d_in[0];
    const float* key   = (const float*)d_in[1];
    const float* att   = (const float*)d_in[2];
    const float* Wq  = (const float*)d_in[3];
    const float* bq  = (const float*)d_in[4];
    const float* Wk  = (const float*)d_in[5];
    const float* bk  = (const float*)d_in[6];
    const float* Wv1 = (const float*)d_in[7];
    const float* bv1 = (const float*)d_in[8];
    const float* Wv2 = (const float*)d_in[9];
    const float* bv2 = (const float*)d_in[10];
    const float* gamma = (const float*)d_in[11];
    const float* beta  = (const float*)d_in[12];
    const float* mean  = (const float*)d_in[13];
    const float* var   = (const float*)d_in[14];

    float* out    = (float*)d_out;
    float* outX   = out;             // [32,512]
    float* outIdx = out + 16384;     // [32,200] idx as float
    float* outA   = out + 22784;     // [32,200,1200]

    char* ws = (char*)d_ws;
    size_t off = 0;
    auto carve = [&](size_t bytes) {
        void* p = ws + off; off += (bytes + 255) & ~(size_t)255; return p;
    };
    int*            idxws = (int*)carve((size_t)NB * LP * 4);
    unsigned short* Wqt   = (unsigned short*)carve((size_t)HID * VD * 2);
    unsigned short* Wkt   = (unsigned short*)carve((size_t)HID * VD * 2);
    unsigned short* Wv1t  = (unsigned short*)carve((size_t)HID * VD * 2);
    unsigned short* Wv2t  = (unsigned short*)carve((size_t)HID * VD * 2);
    unsigned short* Kp    = (unsigned short*)carve((size_t)NB * LQ * HID * 2);  // 39.3 MB
    unsigned short* Qt    = (unsigned short*)carve((size_t)NB * HID * LPP * 2);
    unsigned short* Kt    = (unsigned short*)carve((size_t)NB * HID * LQP * 2);
    unsigned short* V1t   = (unsigned short*)carve((size_t)NB * HID * LPP * 2);
    unsigned short* V2t   = (unsigned short*)carve((size_t)NB * HID * LQP * 2);
    float*          pe    = (float*)carve((size_t)LQ * VD * 4);
    unsigned short* Qp    = (unsigned short*)carve((size_t)NB * LP * HID * 2);
    float*          PEWk  = (float*)carve((size_t)LQP * HID * 4);
    float*          PEWkT = (float*)carve((size_t)HID * LQP * 4);
    float*          PEWq  = (float*)carve((size_t)LPP * HID * 4);
    float*          PEWqT = (float*)carve((size_t)HID * LPP * 4);
    // Mp/Np alias Kp (dead after attnavg): (GM+GN)*4.19MB = 25.2MB <= 39.3MB
    float* Mp = (float*)Kp;
    float* Np = (float*)((char*)Kp + (size_t)GM * 256 * 4096 * 4);
    (void)ws_size; (void)in_sizes; (void)n_in; (void)out_size;

    topk_kernel<<<dim3(NB), dim3(1024), 0, stream>>>(att, idxws, outIdx);
    prep_kernel<<<dim3(664), dim3(256), 0, stream>>>(
        pe, Wq, Wk, Wv1, Wv2, Wqt, Wkt, Wv1t, Wv2t);
    pew_kernel<<<dim3(12, 4), dim3(256), 0, stream>>>(
        pe, Wkt, Wqt, bk, bq, PEWk, PEWkT, PEWq, PEWqT);

    proj_kernel<<<dim3(144, 1, NB), dim3(256), 0, stream>>>(
        query, key, idxws, Wqt, Wkt, Wv1t, Wv2t, bv1, bv2,
        PEWk, PEWkT, PEWq, PEWqT, Qp, Kp, Qt, Kt, V1t, V2t);

    attnavg_kernel<<<dim3(10, 2, NB), dim3(256), 0, stream>>>(Qp, Kp, outA);

    pair_kernel<<<dim3(GM + GN, 256), dim3(64), 0, stream>>>(
        Kt, V2t, Qt, V1t, Mp, Np);

    xout_kernel<<<dim3(256), dim3(256), 0, stream>>>(
        Mp, Np, gamma, beta, mean, var, outX);
}

// Round 8
// 301.808 us; speedup vs baseline: 1.2687x; 1.2687x over previous
//
#include <hip/hip_runtime.h>
#include <hip/hip_bf16.h>

#define NB 32
#define LV 1000
#define LQ 1200
#define VD 128
#define HID 512
#define NH 8
#define HD 64
#define LP 200    // len_pro = 0.2 * 1000
#define LQP 1216  // LQ padded to mult of 64
#define LPP 256   // LP padded
#define GM 4      // K-split slabs for pairM
#define GN 2      // K-split slabs for pairN

typedef __attribute__((ext_vector_type(8))) short s8v;   // 8 x bf16 (4 VGPR)
typedef __attribute__((ext_vector_type(4))) float f4v;   // 4 x f32 acc

union FragU { s8v v; unsigned short u[8]; };

__device__ __forceinline__ unsigned short f2bf(float f) {
    __hip_bfloat16 h = __float2bfloat16(f);
    return *reinterpret_cast<unsigned short*>(&h);
}

// ---------------------------------------------------------------------------
// K1: scores = max over 4 rows of att; stable top-200 via bitonic sort.
// ---------------------------------------------------------------------------
__global__ __launch_bounds__(1024) void topk_kernel(const float* __restrict__ att,
                                                    int* __restrict__ idx_ws,
                                                    float* __restrict__ out_idx) {
    __shared__ float s[1024];
    __shared__ int   si[1024];
    int b = blockIdx.x, tid = threadIdx.x;
    {
        float v = -INFINITY;
        if (tid < LV) {
            const float* p = att + (size_t)b * 4 * LV + tid;
            v = fmaxf(fmaxf(p[0], p[LV]), fmaxf(p[2 * LV], p[3 * LV]));
        }
        s[tid] = v; si[tid] = tid;
    }
    __syncthreads();
    for (int k = 2; k <= 1024; k <<= 1) {
        for (int j = k >> 1; j > 0; j >>= 1) {
            int i = tid, l = i ^ j;
            if (l > i) {
                float a = s[i], c = s[l];
                int ia = si[i], ic = si[l];
                bool aFirst = (a > c) || (a == c && ia < ic);
                bool desc = ((i & k) == 0);
                if (desc != aFirst) { s[i] = c; s[l] = a; si[i] = ic; si[l] = ia; }
            }
            __syncthreads();
        }
    }
    if (tid < LP) {
        int v = si[tid];
        idx_ws[b * LP + tid]  = v;
        out_idx[b * LP + tid] = (float)v;
    }
}

// ---------------------------------------------------------------------------
// K2: prep = pe_fill (blocks 0..599) + weight transpose (blocks 600..663)
// ---------------------------------------------------------------------------
__global__ __launch_bounds__(256) void prep_kernel(
    float* __restrict__ pe,
    const float* __restrict__ w0, const float* __restrict__ w1,
    const float* __restrict__ w2, const float* __restrict__ w3,
    unsigned short* __restrict__ t0, unsigned short* __restrict__ t1,
    unsigned short* __restrict__ t2, unsigned short* __restrict__ t3)
{
    __shared__ unsigned short Ts[64][72];
    int bx = blockIdx.x, tid = threadIdx.x;
    if (bx < 600) {
        int t = bx * 256 + tid;
        if (t < LQ * VD) {
            int r = t >> 7, c = t & 127;
            int i = c >> 1;
            float div = expf((float)(2 * i) * -0.07195578415606394f);
            float ang = (float)r * div;
            pe[t] = (c & 1) ? cosf(ang) : sinf(ang);
        }
        return;
    }
    int idx = bx - 600;          // 0..63
    int mat = idx >> 4, rem = idx & 15;
    int k0 = (rem & 1) * 64, n0 = (rem >> 1) * 64;
    const float* W; unsigned short* T;
    switch (mat) {
        case 0:  W = w0; T = t0; break;
        case 1:  W = w1; T = t1; break;
        case 2:  W = w2; T = t2; break;
        default: W = w3; T = t3; break;
    }
    #pragma unroll
    for (int e = 0; e < 2; ++e) {
        int flat = tid + e * 256;
        int kk = flat >> 3, n8 = (flat & 7) * 8;
        const float* p = W + (size_t)(k0 + kk) * HID + n0 + n8;
        float4 f0 = *(const float4*)p, f1 = *(const float4*)(p + 4);
        Ts[n8 + 0][kk] = f2bf(f0.x); Ts[n8 + 1][kk] = f2bf(f0.y);
        Ts[n8 + 2][kk] = f2bf(f0.z); Ts[n8 + 3][kk] = f2bf(f0.w);
        Ts[n8 + 4][kk] = f2bf(f1.x); Ts[n8 + 5][kk] = f2bf(f1.y);
        Ts[n8 + 6][kk] = f2bf(f1.z); Ts[n8 + 7][kk] = f2bf(f1.w);
    }
    __syncthreads();
    #pragma unroll
    for (int e = 0; e < 2; ++e) {
        int flat = tid + e * 256;
        int nn = flat >> 3, k8 = (flat & 7) * 8;
        uint4 pk;
        pk.x = (unsigned)Ts[nn][k8 + 0] | ((unsigned)Ts[nn][k8 + 1] << 16);
        pk.y = (unsigned)Ts[nn][k8 + 2] | ((unsigned)Ts[nn][k8 + 3] << 16);
        pk.z = (unsigned)Ts[nn][k8 + 4] | ((unsigned)Ts[nn][k8 + 5] << 16);
        pk.w = (unsigned)Ts[nn][k8 + 6] | ((unsigned)Ts[nn][k8 + 7] << 16);
        *(uint4*)&T[(size_t)(n0 + nn) * VD + k0 + k8] = pk;
    }
}

// ---------------------------------------------------------------------------
// K3: PEWT[n][r] = (pe[r] @ W + bias)[n], transposed f32 layout only.
// x<10 -> Wk variant (rows up to 1216), x>=10 -> Wq variant (256).
// ---------------------------------------------------------------------------
__global__ __launch_bounds__(256) void pew_kernel(
    const float* __restrict__ pe,
    const unsigned short* __restrict__ Wkt, const unsigned short* __restrict__ Wqt,
    const float* __restrict__ bk, const float* __restrict__ bq,
    float* __restrict__ PEWkT, float* __restrict__ PEWqT)
{
    int x = blockIdx.x, yb = blockIdx.y;
    bool kMat = (x < 10);
    int rows = kMat ? LQ : LP;
    int Lpad = kMat ? LQP : LPP;
    const unsigned short* Wt = kMat ? Wkt : Wqt;
    const float* bias = kMat ? bk : bq;
    float* PWT = kMat ? PEWkT : PEWqT;
    int xb = kMat ? x : x - 10;
    int lane = threadIdx.x & 63, w = threadIdx.x >> 6;
    int rbase = xb * 128 + (w >> 1) * 64;
    int nbase = yb * 128 + (w & 1) * 64;
    if (rbase >= Lpad) return;
    int lc = lane & 15, lg = lane >> 4;

    int prow[4];
    #pragma unroll
    for (int i = 0; i < 4; ++i) prow[i] = min(rbase + i * 16 + lc, rows - 1);

    f4v acc[4][4] = {};
    for (int kk = 0; kk < VD; kk += 32) {
        s8v af[4], bfr[4];
        #pragma unroll
        for (int i = 0; i < 4; ++i) {
            const float* pp = pe + (size_t)prow[i] * VD + kk + lg * 8;
            float4 f0 = *(const float4*)pp, f1 = *(const float4*)(pp + 4);
            FragU fu;
            fu.u[0]=f2bf(f0.x); fu.u[1]=f2bf(f0.y); fu.u[2]=f2bf(f0.z); fu.u[3]=f2bf(f0.w);
            fu.u[4]=f2bf(f1.x); fu.u[5]=f2bf(f1.y); fu.u[6]=f2bf(f1.z); fu.u[7]=f2bf(f1.w);
            af[i] = fu.v;
        }
        #pragma unroll
        for (int j = 0; j < 4; ++j)
            bfr[j] = *(const s8v*)&Wt[(size_t)(nbase + j * 16 + lc) * VD + kk + lg * 8];
        #pragma unroll
        for (int i = 0; i < 4; ++i)
            #pragma unroll
            for (int j = 0; j < 4; ++j)
                acc[i][j] = __builtin_amdgcn_mfma_f32_16x16x32_bf16(bfr[j], af[i], acc[i][j], 0, 0, 0);
    }
    #pragma unroll
    for (int i = 0; i < 4; ++i) {
        int r = rbase + i * 16 + lc;
        #pragma unroll
        for (int j = 0; j < 4; ++j) {
            int n0 = nbase + j * 16 + lg * 4;
            float4 b4 = *(const float4*)&bias[n0];
            PWT[(size_t)(n0 + 0) * Lpad + r] = acc[i][j][0] + b4.x;
            PWT[(size_t)(n0 + 1) * Lpad + r] = acc[i][j][1] + b4.y;
            PWT[(size_t)(n0 + 2) * Lpad + r] = acc[i][j][2] + b4.z;
            PWT[(size_t)(n0 + 3) * Lpad + r] = acc[i][j][3] + b4.w;
        }
    }
}

// ---------------------------------------------------------------------------
// K4: fused projections. One block per 64-row strip (id<19: key family,
// id>=19: gathered-query family). A-tile staged ONCE in LDS as bf16; each
// wave computes {WtA(PE via PEWT), WtB(bias)} x {2 n-tiles of 64}. Epilogues
// LDS-repacked per wave (coalesced 16B stores): transposed for all outputs,
// row-major additionally for the PE matrix (Kp/Qp).
// ---------------------------------------------------------------------------
__global__ __launch_bounds__(256) void proj_kernel(
    const float* __restrict__ query, const float* __restrict__ key,
    const int* __restrict__ idxws,
    const unsigned short* __restrict__ Wqt, const unsigned short* __restrict__ Wkt,
    const unsigned short* __restrict__ Wv1t, const unsigned short* __restrict__ Wv2t,
    const float* __restrict__ bv1, const float* __restrict__ bv2,
    const float* __restrict__ PEWkT, const float* __restrict__ PEWqT,
    unsigned short* __restrict__ Qp, unsigned short* __restrict__ Kp,
    unsigned short* __restrict__ Qt, unsigned short* __restrict__ Kt,
    unsigned short* __restrict__ V1t, unsigned short* __restrict__ V2t)
{
    __shared__ unsigned short As[64][136];       // staged A-tile (bf16)
    __shared__ unsigned short Tls[4][64][72];    // per-wave repack tile
    int id = blockIdx.x, b = blockIdx.z, tid = threadIdx.x;
    bool qv = (id >= 19);
    int xb = qv ? id - 19 : id;
    const float* src = qv ? query : key;
    int srcRows = qv ? LV : LQ;
    int rows = qv ? LP : LQ;
    int Lpad = qv ? LPP : LQP;
    const unsigned short* WtA = qv ? Wqt : Wkt;
    const unsigned short* WtB = qv ? Wv1t : Wv2t;
    const float* PWT  = qv ? PEWqT : PEWkT;
    const float* biasB = qv ? bv1 : bv2;
    unsigned short* dT_A = qv ? Qt : Kt;
    unsigned short* dT_B = qv ? V1t : V2t;
    unsigned short* dR_A = qv ? Qp : Kp;
    int r0 = xb * 64;

    // ---- stage A: 64 rows x 128 k, fp32 -> bf16, pad rows zero ----
    #pragma unroll
    for (int e = 0; e < 4; ++e) {
        int f = tid + e * 256;          // 0..1023
        int r = f >> 4, g = (f & 15) * 8;
        int gr = r0 + r;
        uint4 pk = {0u, 0u, 0u, 0u};
        if (gr < rows) {
            int sr = qv ? idxws[b * LP + gr] : gr;
            const float* p = src + ((size_t)b * srcRows + sr) * VD + g;
            float4 f0 = *(const float4*)p, f1 = *(const float4*)(p + 4);
            pk.x = (unsigned)f2bf(f0.x) | ((unsigned)f2bf(f0.y) << 16);
            pk.y = (unsigned)f2bf(f0.z) | ((unsigned)f2bf(f0.w) << 16);
            pk.z = (unsigned)f2bf(f1.x) | ((unsigned)f2bf(f1.y) << 16);
            pk.w = (unsigned)f2bf(f1.z) | ((unsigned)f2bf(f1.w) << 16);
        }
        *(uint4*)&As[r][g] = pk;
    }
    __syncthreads();

    int lane = tid & 63, w = tid >> 6;
    int lc = lane & 15, lg = lane >> 4;
    unsigned short* Tw = &Tls[w][0][0];

    #pragma unroll
    for (int m = 0; m < 2; ++m) {
        const unsigned short* Wt = m ? WtB : WtA;
        #pragma unroll
        for (int nt = 0; nt < 2; ++nt) {
            int n0 = w * 128 + nt * 64;
            f4v acc[4][4] = {};
            #pragma unroll
            for (int ki = 0; ki < 4; ++ki) {
                int kk = ki * 32 + lg * 8;
                s8v af[4], bfr[4];
                #pragma unroll
                for (int i = 0; i < 4; ++i)
                    af[i] = *(const s8v*)&As[i * 16 + lc][kk];
                #pragma unroll
                for (int j = 0; j < 4; ++j)
                    bfr[j] = *(const s8v*)&Wt[(size_t)(n0 + j * 16 + lc) * VD + kk];
                #pragma unroll
                for (int i = 0; i < 4; ++i)
                    #pragma unroll
                    for (int j = 0; j < 4; ++j)
                        acc[i][j] = __builtin_amdgcn_mfma_f32_16x16x32_bf16(
                            af[i], bfr[j], acc[i][j], 0, 0, 0);
            }

            // ---- pack to bf16 pairs (PEW add for m==0, bias for m==1) ----
            uint2 pk[4][4];
            if (m == 0) {
                #pragma unroll
                for (int i = 0; i < 4; ++i) {
                    int rb = r0 + i * 16 + lg * 4;
                    #pragma unroll
                    for (int j = 0; j < 4; ++j) {
                        int n = n0 + j * 16 + lc;
                        float4 t4 = *(const float4*)&PWT[(size_t)n * Lpad + rb];
                        unsigned h0 = (rb + 0 < rows) ? f2bf(acc[i][j][0] + t4.x) : 0u;
                        unsigned h1 = (rb + 1 < rows) ? f2bf(acc[i][j][1] + t4.y) : 0u;
                        unsigned h2 = (rb + 2 < rows) ? f2bf(acc[i][j][2] + t4.z) : 0u;
                        unsigned h3 = (rb + 3 < rows) ? f2bf(acc[i][j][3] + t4.w) : 0u;
                        pk[i][j].x = h0 | (h1 << 16);
                        pk[i][j].y = h2 | (h3 << 16);
                    }
                }
            } else {
                float bb[4];
                #pragma unroll
                for (int j = 0; j < 4; ++j) bb[j] = biasB[n0 + j * 16 + lc];
                #pragma unroll
                for (int i = 0; i < 4; ++i) {
                    int rb = r0 + i * 16 + lg * 4;
                    #pragma unroll
                    for (int j = 0; j < 4; ++j) {
                        unsigned h0 = (rb + 0 < rows) ? f2bf(acc[i][j][0] + bb[j]) : 0u;
                        unsigned h1 = (rb + 1 < rows) ? f2bf(acc[i][j][1] + bb[j]) : 0u;
                        unsigned h2 = (rb + 2 < rows) ? f2bf(acc[i][j][2] + bb[j]) : 0u;
                        unsigned h3 = (rb + 3 < rows) ? f2bf(acc[i][j][3] + bb[j]) : 0u;
                        pk[i][j].x = h0 | (h1 << 16);
                        pk[i][j].y = h2 | (h3 << 16);
                    }
                }
            }

            // ---- transposed repack: Tw[n][r], b64 writes, 16B reads/stores ----
            #pragma unroll
            for (int i = 0; i < 4; ++i)
                #pragma unroll
                for (int j = 0; j < 4; ++j)
                    *(uint2*)&Tw[(j * 16 + lc) * 72 + i * 16 + lg * 4] = pk[i][j];
            unsigned short* dT = m ? dT_B : dT_A;
            #pragma unroll
            for (int e = 0; e < 8; ++e) {
                int c = lane + e * 64;
                int nn = c >> 3, cc = (c & 7) * 8;
                s8v v = *(const s8v*)&Tw[nn * 72 + cc];
                *(s8v*)&dT[((size_t)b * HID + n0 + nn) * Lpad + r0 + cc] = v;
            }

            // ---- row-major repack (PE matrix only): Tw[r][n] ----
            if (m == 0) {
                #pragma unroll
                for (int i = 0; i < 4; ++i) {
                    int rr = i * 16 + lg * 4;
                    #pragma unroll
                    for (int j = 0; j < 4; ++j) {
                        int nn = j * 16 + lc;
                        Tw[(rr + 0) * 72 + nn] = (unsigned short)(pk[i][j].x & 0xffff);
                        Tw[(rr + 1) * 72 + nn] = (unsigned short)(pk[i][j].x >> 16);
                        Tw[(rr + 2) * 72 + nn] = (unsigned short)(pk[i][j].y & 0xffff);
                        Tw[(rr + 3) * 72 + nn] = (unsigned short)(pk[i][j].y >> 16);
                    }
                }
                #pragma unroll
                for (int e = 0; e < 8; ++e) {
                    int c = lane + e * 64;
                    int rr = c >> 3, cc = (c & 7) * 8;
                    int gr = r0 + rr;
                    if (gr < rows) {
                        s8v v = *(const s8v*)&Tw[rr * 72 + cc];
                        *(s8v*)&dR_A[((size_t)b * rows + gr) * HID + n0 + cc] = v;
                    }
                }
            }
        }
    }
}

// ---------------------------------------------------------------------------
// K5: attn_avg[b,v,q] = (Qp[b,v,:].Kp[b,q,:]) / 64 — swapped MFMA so regs
// hold 4 consecutive q at fixed v: direct float4 stores (64B segments).
// ---------------------------------------------------------------------------
__global__ __launch_bounds__(256) void attnavg_kernel(
    const unsigned short* __restrict__ Qp, const unsigned short* __restrict__ Kp,
    float* __restrict__ outA)
{
    int b = blockIdx.z;
    int lane = threadIdx.x & 63, w = threadIdx.x >> 6;
    int vbase = blockIdx.y * 128 + (w >> 1) * 64;
    int qbase = blockIdx.x * 128 + (w & 1) * 64;
    if (qbase >= LQ || vbase >= LP) return;
    int lc = lane & 15, lg = lane >> 4;

    int qr[4], vr[4];
    #pragma unroll
    for (int i = 0; i < 4; ++i) qr[i] = min(qbase + i * 16 + lc, LQ - 1);
    #pragma unroll
    for (int j = 0; j < 4; ++j) vr[j] = min(vbase + j * 16 + lc, LP - 1);

    f4v acc[4][4] = {};   // acc[i=q-frag][j=v-frag]
    for (int kk = 0; kk < HID; kk += 32) {
        s8v af[4], bfr[4];
        #pragma unroll
        for (int i = 0; i < 4; ++i)
            af[i] = *(const s8v*)&Kp[((size_t)b * LQ + qr[i]) * HID + kk + lg * 8];
        #pragma unroll
        for (int j = 0; j < 4; ++j)
            bfr[j] = *(const s8v*)&Qp[((size_t)b * LP + vr[j]) * HID + kk + lg * 8];
        #pragma unroll
        for (int i = 0; i < 4; ++i)
            #pragma unroll
            for (int j = 0; j < 4; ++j)
                acc[i][j] = __builtin_amdgcn_mfma_f32_16x16x32_bf16(af[i], bfr[j], acc[i][j], 0, 0, 0);
    }
    const float sc = 1.0f / 64.0f;
    #pragma unroll
    for (int j = 0; j < 4; ++j) {
        int v = vbase + j * 16 + lc;
        if (v >= LP) continue;
        float* base = outA + ((size_t)b * LP + v) * LQ;
        #pragma unroll
        for (int i = 0; i < 4; ++i) {
            int q0 = qbase + i * 16 + lg * 4;
            if (q0 + 3 >= LQ) continue;
            float4 o = {acc[i][j][0] * sc, acc[i][j][1] * sc,
                        acc[i][j][2] * sc, acc[i][j][3] * sc};
            *(float4*)&base[q0] = o;
        }
    }
}

// ---------------------------------------------------------------------------
// K6: merged pair GEMMs: M = Kt~V2t (GM slabs), N = Qt~V1t (GN slabs).
// out[d][k] = sum_r A[r,d]*B[r,k]; swapped MFMA -> float4 stores.
// ---------------------------------------------------------------------------
__global__ __launch_bounds__(64) void pair_kernel(
    const unsigned short* __restrict__ Kt, const unsigned short* __restrict__ V2t,
    const unsigned short* __restrict__ Qt, const unsigned short* __restrict__ V1t,
    float* __restrict__ Mp, float* __restrict__ Np)
{
    int g = blockIdx.x;
    const unsigned short *At, *Bt; float* outP;
    int LPAD, NCH, G, slab;
    if (g < GM) { At = Kt; Bt = V2t; outP = Mp; LPAD = LQP; NCH = 38; G = GM; slab = g; }
    else        { At = Qt; Bt = V1t; outP = Np; LPAD = LPP; NCH = 8;  G = GN; slab = g - GM; }
    int bh = blockIdx.y, b = bh >> 3, h = bh & 7;
    int lane = threadIdx.x, lc = lane & 15, lg = lane >> 4;
    const unsigned short* Ah = At + ((size_t)b * HID + h * HD) * LPAD;
    const unsigned short* Bh = Bt + ((size_t)b * HID + h * HD) * LPAD;
    f4v acc[4][4] = {};
    for (int c = slab; c < NCH; c += G) {
        int r0 = c * 32 + lg * 8;
        s8v af[4], bfr[4];
        #pragma unroll
        for (int i = 0; i < 4; ++i)
            af[i] = *(const s8v*)&Ah[(size_t)(i * 16 + lc) * LPAD + r0];
        #pragma unroll
        for (int j = 0; j < 4; ++j)
            bfr[j] = *(const s8v*)&Bh[(size_t)(j * 16 + lc) * LPAD + r0];
        #pragma unroll
        for (int i = 0; i < 4; ++i)
            #pragma unroll
            for (int j = 0; j < 4; ++j)
                acc[i][j] = __builtin_amdgcn_mfma_f32_16x16x32_bf16(bfr[j], af[i], acc[i][j], 0, 0, 0);
    }
    float* op = outP + ((size_t)slab * 256 + bh) * 4096;
    #pragma unroll
    for (int i = 0; i < 4; ++i) {
        int d = i * 16 + lc;
        #pragma unroll
        for (int j = 0; j < 4; ++j) {
            int k0 = j * 16 + lg * 4;
            float4 o = {acc[i][j][0], acc[i][j][1], acc[i][j][2], acc[i][j][3]};
            *(float4*)&op[d * 64 + k0] = o;
        }
    }
}

// ---------------------------------------------------------------------------
// K7: x[b,h*64+k] = BN((1/8) sum_d (sum_g Mp)(sum_g Np))
// ---------------------------------------------------------------------------
__global__ __launch_bounds__(256) void xout_kernel(
    const float* __restrict__ Mp, const float* __restrict__ Np,
    const float* __restrict__ gamma, const float* __restrict__ beta,
    const float* __restrict__ mean, const float* __restrict__ var,
    float* __restrict__ outX)
{
    int bh = blockIdx.x, b = bh >> 3, h = bh & 7;
    int tid = threadIdx.x;
    int k = tid & 63, dg = tid >> 6;
    float s = 0.f;
    for (int d = dg * 16; d < dg * 16 + 16; ++d) {
        int o = d * 64 + k;
        float m = 0.f, n = 0.f;
        #pragma unroll
        for (int g = 0; g < GM; ++g) m += Mp[((size_t)g * 256 + bh) * 4096 + o];
        #pragma unroll
        for (int g = 0; g < GN; ++g) n += Np[((size_t)g * 256 + bh) * 4096 + o];
        s += m * n;
    }
    __shared__ float red[4][64];
    red[dg][k] = s;
    __syncthreads();
    if (tid < 64) {
        float x = (red[0][tid] + red[1][tid] + red[2][tid] + red[3][tid]) * 0.125f;
        int c = h * HD + tid;
        outX[(size_t)b * HID + c] =
            (x - mean[c]) * rsqrtf(var[c] + 1e-5f) * gamma[c] + beta[c];
    }
}

extern "C" void kernel_launch(void* const* d_in, const int* in_sizes, int n_in,
                              void* d_out, int out_size, void* d_ws, size_t ws_size,
                              hipStream_t stream) {
    const float* query = (const float*)d_in[0];
    const float* key   = (const float*)d_in[1];
    const float* att   = (const float*)d_in[2];
    const float* Wq  = (const float*)d_in[3];
    const float* bq  = (const float*)d_in[4];
    const float* Wk  = (const float*)d_in[5];
    const float* bk  = (const float*)d_in[6];
    const float* Wv1 = (const float*)d_in[7];
    const float* bv1 = (const float*)d_in[8];
    const float* Wv2 = (const float*)d_in[9];
    const float* bv2 = (const float*)d_in[10];
    const float* gamma = (const float*)d_in[11];
    const float* beta  = (const float*)d_in[12];
    const float* mean  = (const float*)d_in[13];
    const float* var   = (const float*)d_in[14];

    float* out    = (float*)d_out;
    float* outX   = out;             // [32,512]
    float* outIdx = out + 16384;     // [32,200] idx as float
    float* outA   = out + 22784;     // [32,200,1200]

    char* ws = (char*)d_ws;
    size_t off = 0;
    auto carve = [&](size_t bytes) {
        void* p = ws + off; off += (bytes + 255) & ~(size_t)255; return p;
    };
    int*            idxws = (int*)carve((size_t)NB * LP * 4);
    unsigned short* Wqt   = (unsigned short*)carve((size_t)HID * VD * 2);
    unsigned short* Wkt   = (unsigned short*)carve((size_t)HID * VD * 2);
    unsigned short* Wv1t  = (unsigned short*)carve((size_t)HID * VD * 2);
    unsigned short* Wv2t  = (unsigned short*)carve((size_t)HID * VD * 2);
    unsigned short* Kp    = (unsigned short*)carve((size_t)NB * LQ * HID * 2);  // 39.3 MB
    unsigned short* Qt    = (unsigned short*)carve((size_t)NB * HID * LPP * 2);
    unsigned short* Kt    = (unsigned short*)carve((size_t)NB * HID * LQP * 2);
    unsigned short* V1t   = (unsigned short*)carve((size_t)NB * HID * LPP * 2);
    unsigned short* V2t   = (unsigned short*)carve((size_t)NB * HID * LQP * 2);
    float*          pe    = (float*)carve((size_t)LQ * VD * 4);
    unsigned short* Qp    = (unsigned short*)carve((size_t)NB * LP * HID * 2);
    float*          PEWkT = (float*)carve((size_t)HID * LQP * 4);
    float*          PEWqT = (float*)carve((size_t)HID * LPP * 4);
    // Mp/Np alias Kp (dead after attnavg): (GM+GN)*4.19MB = 25.2MB <= 39.3MB
    float* Mp = (float*)Kp;
    float* Np = (float*)((char*)Kp + (size_t)GM * 256 * 4096 * 4);
    (void)ws_size; (void)in_sizes; (void)n_in; (void)out_size;

    topk_kernel<<<dim3(NB), dim3(1024), 0, stream>>>(att, idxws, outIdx);
    prep_kernel<<<dim3(664), dim3(256), 0, stream>>>(
        pe, Wq, Wk, Wv1, Wv2, Wqt, Wkt, Wv1t, Wv2t);
    pew_kernel<<<dim3(12, 4), dim3(256), 0, stream>>>(
        pe, Wkt, Wqt, bk, bq, PEWkT, PEWqT);

    // fused projections: 19 key-strips + 4 query-strips, per batch
    proj_kernel<<<dim3(23, 1, NB), dim3(256), 0, stream>>>(
        query, key, idxws, Wqt, Wkt, Wv1t, Wv2t, bv1, bv2,
        PEWkT, PEWqT, Qp, Kp, Qt, Kt, V1t, V2t);

    attnavg_kernel<<<dim3(10, 2, NB), dim3(256), 0, stream>>>(Qp, Kp, outA);

    pair_kernel<<<dim3(GM + GN, 256), dim3(64), 0, stream>>>(
        Kt, V2t, Qt, V1t, Mp, Np);

    xout_kernel<<<dim3(256), dim3(256), 0, stream>>>(
        Mp, Np, gamma, beta, mean, var, outX);
}